// Round 12
// baseline (62.307 us; speedup 1.0000x reference)
//
#include <hip/hip_runtime.h>
#include <hip/hip_bf16.h>
#include <math.h>

#define NROWS 8192
#define HALF_N 4096
#define KD 512
#define TILE 128
#define BK 64                     // i8: 64 B per row per K-tile
#define NKT 8                     // KD / BK
#define INV_Q2 (2.0f / 16129.0f)  // TEMP_INV / 127^2
#define NBLK 64
#define NTRI 2080
#define SLOT 8192                 // B-only LDS slot: 128 rows x 64 B

typedef __attribute__((ext_vector_type(4))) int i32x4;

// Kernel 1: row-normalize f32 -> int8 (q = round(127*x/||x||)), zero accums.
__global__ __launch_bounds__(256) void normalize_kernel(const float* __restrict__ X,
                                                        signed char* __restrict__ XN8,
                                                        float* __restrict__ sumexp,
                                                        float* __restrict__ out) {
    const int row = blockIdx.x;
    const int tid = threadIdx.x;
    const int gz = row * 256 + tid;
    if (gz < NROWS) sumexp[gz] = 0.0f;
    if (gz == 0) out[0] = 0.0f;

    const float2 v = reinterpret_cast<const float2*>(X + (size_t)row * KD)[tid];
    float ss = v.x * v.x + v.y * v.y;
    #pragma unroll
    for (int off = 32; off >= 1; off >>= 1) ss += __shfl_xor(ss, off);
    __shared__ float wss[4];
    if ((tid & 63) == 0) wss[tid >> 6] = ss;
    __syncthreads();
    const float tot = wss[0] + wss[1] + wss[2] + wss[3];
    const float scale = 127.0f / fmaxf(sqrtf(tot), 1e-6f);
    char2 o;
    o.x = (signed char)__float2int_rn(v.x * scale);
    o.y = (signed char)__float2int_rn(v.y * scale);
    *reinterpret_cast<char2*>(XN8 + (size_t)row * KD + 2 * tid) = o;
}

#define SB __builtin_amdgcn_sched_barrier(0)

// Supertile decode (R7-proven): 4x4 grid of 16x16-block supertiles, bi <= bj.
__device__ __forceinline__ void decode_tri(int b, int& bi, int& bj) {
    const int pref[10] = {136, 392, 648, 904, 1040, 1296, 1552, 1688, 1944, 2080};
    const int sij[10]  = {0x00, 0x01, 0x02, 0x03, 0x11, 0x12, 0x13, 0x22, 0x23, 0x33};
    int st = 0;
    #pragma unroll
    for (int k = 0; k < 9; ++k) st += (b >= pref[k]);
    const int base = st ? pref[st - 1] : 0;
    const int L = b - base;
    const int si = sij[st] >> 4, sj = sij[st] & 15;
    int li, lj;
    if (si == sj) {
        li = (int)(16.5f - sqrtf(16.5f * 16.5f - 2.0f * (float)L));
        while ((li + 1) * (33 - (li + 1)) / 2 <= L) ++li;
        while (li * (33 - li) / 2 > L) --li;
        lj = li + (L - li * (33 - li) / 2);
    } else {
        li = L >> 4;
        lj = L & 15;
        if (li & 1) lj = 15 - lj;
    }
    bi = si * 16 + li;
    bj = sj * 16 + lj;
}

// Kernel 2: int8 128x128-tile GEMM (S ~ XN*XN^T / 127^2). A: direct
// global->reg loads (L2-resident table), double-buffered one phase ahead.
// B: 3-slot gload_lds pipeline with proven 0-conflict chunk swizzle.
// Ledger (sim-verified): phase t issues [A(t+1) x4, Bg(t+2) x2];
// vmcnt(8) before MFMA retires A(t); vmcnt(6) before end barrier retires
// Bg(t+1), so the barrier makes slot t+1 collectively ready. Never drains.
__global__ __launch_bounds__(256, 4) void gemm_fused_kernel(const signed char* __restrict__ XN8,
                                                            float* __restrict__ sumexp,
                                                            float* __restrict__ poslogit) {
    __shared__ __align__(16) unsigned char lds[3 * SLOT];   // 24 KB -> 4 blocks/CU

    const int b = (blockIdx.x & 7) * (NTRI / 8) + (blockIdx.x >> 3);
    int bi, bj;
    decode_tri(b, bi, bj);

    const int rowBase = bi * TILE;
    const int colBase = bj * TILE;

    const int tid  = threadIdx.x;
    const int lane = tid & 63;
    const int wid  = tid >> 6;          // 0..3
    const int wr   = wid >> 1;          // 0/1  (64 output rows per wave)
    const int wc   = wid & 1;           // 0/1  (64 output cols per wave)
    const int l15  = lane & 15;
    const int l4   = lane >> 4;

    // A fragment pointers: 16 contiguous bytes per lane, full-sector coalesced.
    const signed char* aP[4];
    #pragma unroll
    for (int m = 0; m < 4; ++m)
        aP[m] = XN8 + (size_t)(rowBase + wr * 64 + m * 16 + l15) * KD + l4 * 16;

    // B in-slot read offsets (proven swizzle cp = l4 ^ ((l15>>1)&3)).
    const int cp = l4 ^ ((l15 >> 1) & 3);
    int bOff[4];
    #pragma unroll
    for (int n = 0; n < 4; ++n) bOff[n] = (wc * 64 + n * 16 + l15) * 64 + cp * 16;

    // B stage addressing: 512 chunks/tile, 2 per thread (c = tid, tid+256).
    const int r0 = tid >> 2, r1 = (tid + 256) >> 2;
    const int s0 = (tid & 3) ^ ((r0 >> 1) & 3);
    const int s1 = (tid & 3) ^ ((r1 >> 1) & 3);
    const signed char* gB0 = XN8 + (size_t)(colBase + r0) * KD + s0 * 16;
    const signed char* gB1 = XN8 + (size_t)(colBase + r1) * KD + s1 * 16;
    const int ldsB0 = tid * 16;
    const int ldsB1 = (tid + 256) * 16;

#define STAGE_B(T) do {                                                          \
    unsigned char* slot = lds + ((T) % 3) * SLOT;                                \
    __builtin_amdgcn_global_load_lds(                                            \
        (const __attribute__((address_space(1))) void*)(gB0 + (T) * BK),         \
        (__attribute__((address_space(3))) void*)(slot + ldsB0), 16, 0, 0);      \
    __builtin_amdgcn_global_load_lds(                                            \
        (const __attribute__((address_space(1))) void*)(gB1 + (T) * BK),         \
        (__attribute__((address_space(3))) void*)(slot + ldsB1), 16, 0, 0);      \
  } while (0)

#define LOAD_A(DST, T) do {                                                      \
    _Pragma("unroll")                                                            \
    for (int m = 0; m < 4; ++m) DST[m] = *(const i32x4*)(aP[m] + (T) * BK);      \
  } while (0)

// Phase: [load A(t+1) -> ANEXT][stage B(t+2)] | ds_read B(t) | vmcnt(VA) |
// lgkm(0) | setprio(1) 16 MFMA with AUSE setprio(0) | vmcnt(VB) | barrier.
#define PH(T, AUSE, ANEXT, STAGE, VA, VB, LASTBAR) do {                          \
    const unsigned char* Bs = lds + ((T) % 3) * SLOT;                            \
    if ((T) < NKT - 1) LOAD_A(ANEXT, (T) + 1);                                   \
    SB;                                                                          \
    STAGE;                                                                       \
    SB;                                                                          \
    i32x4 bV[4];                                                                 \
    _Pragma("unroll")                                                            \
    for (int n = 0; n < 4; ++n) bV[n] = *(const i32x4*)(Bs + bOff[n]);           \
    SB;                                                                          \
    asm volatile("s_waitcnt vmcnt(" #VA ")" ::: "memory");                       \
    SB;                                                                          \
    asm volatile("s_waitcnt lgkmcnt(0)" ::: "memory");                           \
    SB;                                                                          \
    __builtin_amdgcn_s_setprio(1);                                               \
    _Pragma("unroll")                                                            \
    for (int m = 0; m < 4; ++m)                                                  \
        _Pragma("unroll")                                                        \
        for (int n = 0; n < 4; ++n)                                              \
            acc[m][n] = __builtin_amdgcn_mfma_i32_16x16x64_i8(                   \
                AUSE[m], bV[n], acc[m][n], 0, 0, 0);                             \
    __builtin_amdgcn_s_setprio(0);                                               \
    if (VB >= 0) { asm volatile("s_waitcnt vmcnt(%0)" :: "i"(VB) : "memory"); SB; } \
    if (LASTBAR) __builtin_amdgcn_s_barrier();                                   \
    SB;                                                                          \
  } while (0)

    i32x4 acc[4][4] = {};
    i32x4 aC[4], aN[4];

    // Prologue (ledger: issue Bg0 x2, A0 x4, Bg1 x2; vmcnt(2) retires Bg0+A0).
    STAGE_B(0);
    LOAD_A(aC, 0);
    STAGE_B(1);
    asm volatile("s_waitcnt vmcnt(2)" ::: "memory");
    SB;
    __builtin_amdgcn_s_barrier();

    PH(0, aC, aN, STAGE_B(2), 8, 6, 1);
    PH(1, aN, aC, STAGE_B(3), 8, 6, 1);
    PH(2, aC, aN, STAGE_B(4), 8, 6, 1);
    PH(3, aN, aC, STAGE_B(5), 8, 6, 1);
    PH(4, aC, aN, STAGE_B(6), 8, 6, 1);
    PH(5, aN, aC, STAGE_B(7), 8, 6, 1);
    PH(6, aC, aN, , 6, 4, 1);
    PH(7, aN, aC, , 0, -1, 0);

    __syncthreads();   // protect LDS overlay

    // Epilogue. C/D map: col = l15, row = l4*4 + reg. logit = acc * 2/127^2.
    // Universal rule: count only gcol > grow; add to rowsum AND colsum
    // (handles diagonal tiles without a split; mirrors come via colsum).
    float* rowsum = (float*)lds;          // [128]
    float* colsum = rowsum + TILE;        // [128]
    if (tid < TILE) { rowsum[tid] = 0.0f; colsum[tid] = 0.0f; }
    __syncthreads();

    float cs[4] = {0.0f, 0.0f, 0.0f, 0.0f};
    #pragma unroll
    for (int m = 0; m < 4; ++m) {
        #pragma unroll
        for (int r = 0; r < 4; ++r) {
            const int row_l = wr * 64 + m * 16 + l4 * 4 + r;
            const int grow = rowBase + row_l;
            const int prow = grow < HALF_N ? grow + HALF_N : grow - HALF_N;
            float p = 0.0f;
            #pragma unroll
            for (int n = 0; n < 4; ++n) {
                const int gcol = colBase + wc * 64 + n * 16 + l15;
                const float s = (float)acc[m][n][r] * INV_Q2;
                const bool up = (gcol > grow);
                const float e = up ? __expf(s) : 0.0f;
                p += e;
                cs[n] += e;
                if (up && gcol == prow) {      // single upper occurrence
                    poslogit[grow] = s;
                    poslogit[gcol] = s;        // mirrored entry (pos involution)
                }
            }
            p += __shfl_xor(p, 1);
            p += __shfl_xor(p, 2);
            p += __shfl_xor(p, 4);
            p += __shfl_xor(p, 8);
            if (l15 == 0) atomicAdd(&rowsum[row_l], p);
        }
    }
    #pragma unroll
    for (int n = 0; n < 4; ++n) {
        float c = cs[n];
        c += __shfl_xor(c, 16);
        c += __shfl_xor(c, 32);
        if (l4 == 0) atomicAdd(&colsum[wc * 64 + n * 16 + l15], c);
    }
    __syncthreads();
    if (tid < TILE) {
        atomicAdd(&sumexp[rowBase + tid], rowsum[tid]);
        atomicAdd(&sumexp[colBase + tid], colsum[tid]);
    }
#undef STAGE_B
#undef LOAD_A
#undef PH
}

// Kernel 3: loss = sum_i log(sumexp_i) - poslogit_i
__global__ __launch_bounds__(256) void finalize_kernel(const float* __restrict__ sumexp,
                                                       const float* __restrict__ poslogit,
                                                       float* __restrict__ out) {
    const int i = blockIdx.x * 256 + threadIdx.x;
    float li = logf(sumexp[i]) - poslogit[i];
    #pragma unroll
    for (int off = 32; off >= 1; off >>= 1) li += __shfl_xor(li, off);
    __shared__ float wss[4];
    if ((threadIdx.x & 63) == 0) wss[threadIdx.x >> 6] = li;
    __syncthreads();
    if (threadIdx.x == 0) atomicAdd(out, wss[0] + wss[1] + wss[2] + wss[3]);
}

extern "C" void kernel_launch(void* const* d_in, const int* in_sizes, int n_in,
                              void* d_out, int out_size, void* d_ws, size_t ws_size,
                              hipStream_t stream) {
    const float* X = (const float*)d_in[0];
    float* out = (float*)d_out;

    signed char* XN8 = (signed char*)d_ws;                            // 4 MB int8
    float* sumexp   = (float*)((char*)d_ws + (size_t)NROWS * KD);     // 32 KB
    float* poslogit = sumexp + NROWS;                                 // 32 KB

    normalize_kernel<<<NROWS, 256, 0, stream>>>(X, XN8, sumexp, out);
    gemm_fused_kernel<<<NTRI, 256, 0, stream>>>(XN8, sumexp, poslogit);
    finalize_kernel<<<NROWS / 256, 256, 0, stream>>>(sumexp, poslogit, out);
}